// Round 1
// baseline (452.043 us; speedup 1.0000x reference)
//
#include <hip/hip_runtime.h>
#include <cstddef>

#define N_NODES 50000
#define N_EDGES 800000
#define FIN     128
#define NH      4
#define FOUT    16
#define COUT    64   // NH*FOUT

// ---------------------------------------------------------------------------
// K1: fused projection GEMM.
//   proj[n, 0:64]  = x[n,:] @ w_proj.T      -> ws
//   skip[n, 0:64]  = x[n,:] @ w_skip.T      -> written to d_out (agg base)
//   s_src[n, h]    = sum_f proj[n,h,f]*a_src[h,f]
//   s_trg[n, h]    = sum_f proj[n,h,f]*a_trg[h,f]
// Block: 256 threads = 8 "ty" row-groups (4 nodes each = 32 nodes) x 32 "tx"
// col-groups (4 cols each = 128 cols; tx<16 -> proj cols, tx>=16 -> skip cols).
// ---------------------------------------------------------------------------
__global__ __launch_bounds__(256) void k1_proj(
    const float* __restrict__ x,
    const float* __restrict__ wproj, const float* __restrict__ wskip,
    const float* __restrict__ asrc,  const float* __restrict__ atrg,
    float* __restrict__ proj, float* __restrict__ ssrc, float* __restrict__ strg,
    float* __restrict__ outv)
{
    __shared__ float xs[32][FIN];
    const int t  = threadIdx.x;
    const int n0 = blockIdx.x * 32;

    // stage 32 x-rows (clamped) : 1024 float4 slots, 4 per thread
    #pragma unroll
    for (int i = 0; i < 4; ++i) {
        int idx = t + i * 256;          // 0..1023
        int r   = idx >> 5;             // 32 float4 per row
        int c   = (idx & 31) * 4;
        int rr  = n0 + r; if (rr >= N_NODES) rr = N_NODES - 1;
        *reinterpret_cast<float4*>(&xs[r][c]) =
            *reinterpret_cast<const float4*>(x + (size_t)rr * FIN + c);
    }
    __syncthreads();

    const int ty = t >> 5;              // 0..7 -> nodes r0..r0+3
    const int tx = t & 31;              // 0..31 -> 4 cols each
    const int r0 = ty * 4;
    const bool isSkip = (tx >= 16);
    const int cc = (tx & 15) * 4;       // col within 64
    const float* __restrict__ W = isSkip ? wskip : wproj;

    float acc[4][4];
    #pragma unroll
    for (int a = 0; a < 4; ++a)
        #pragma unroll
        for (int b = 0; b < 4; ++b) acc[a][b] = 0.f;

    for (int k = 0; k < FIN; k += 4) {
        float4 wv[4];
        #pragma unroll
        for (int b = 0; b < 4; ++b)
            wv[b] = *reinterpret_cast<const float4*>(W + (size_t)(cc + b) * FIN + k);
        #pragma unroll
        for (int a = 0; a < 4; ++a) {
            float4 xv = *reinterpret_cast<const float4*>(&xs[r0 + a][k]);
            #pragma unroll
            for (int b = 0; b < 4; ++b)
                acc[a][b] += xv.x * wv[b].x + xv.y * wv[b].y
                           + xv.z * wv[b].z + xv.w * wv[b].w;
        }
    }

    if (!isSkip) {
        const int h  = tx >> 2;         // head of these 4 cols
        const int f0 = cc & 15;         // feature offset within head
        const float as0 = asrc[h * FOUT + f0 + 0], as1 = asrc[h * FOUT + f0 + 1],
                    as2 = asrc[h * FOUT + f0 + 2], as3 = asrc[h * FOUT + f0 + 3];
        const float at0 = atrg[h * FOUT + f0 + 0], at1 = atrg[h * FOUT + f0 + 1],
                    at2 = atrg[h * FOUT + f0 + 2], at3 = atrg[h * FOUT + f0 + 3];
        #pragma unroll
        for (int a = 0; a < 4; ++a) {
            int n = n0 + r0 + a;
            float4 v = make_float4(acc[a][0], acc[a][1], acc[a][2], acc[a][3]);
            float ps = v.x * as0 + v.y * as1 + v.z * as2 + v.w * as3;
            float pt = v.x * at0 + v.y * at1 + v.z * at2 + v.w * at3;
            // reduce over the 4 tx-lanes of this head (lane bits 0,1)
            ps += __shfl_xor(ps, 1); ps += __shfl_xor(ps, 2);
            pt += __shfl_xor(pt, 1); pt += __shfl_xor(pt, 2);
            if (n < N_NODES) {
                *reinterpret_cast<float4*>(proj + (size_t)n * COUT + cc) = v;
                if ((tx & 3) == 0) {
                    ssrc[(size_t)n * NH + h] = ps;
                    strg[(size_t)n * NH + h] = pt;
                }
            }
        }
    } else {
        #pragma unroll
        for (int a = 0; a < 4; ++a) {
            int n = n0 + r0 + a;
            if (n < N_NODES) {
                float4 v = make_float4(acc[a][0], acc[a][1], acc[a][2], acc[a][3]);
                *reinterpret_cast<float4*>(outv + (size_t)n * COUT + cc) = v;
            }
        }
    }
}

// ---------------------------------------------------------------------------
// K2: per-edge scores. es[e,h] = exp(leaky_relu(s_src[src]+s_trg[trg]));
//     denom[trg,h] += es  (atomic). Global-max shift omitted (invariant).
// ---------------------------------------------------------------------------
__global__ __launch_bounds__(256) void k2_score(
    const int* __restrict__ ei,
    const float* __restrict__ ssrc, const float* __restrict__ strg,
    float* __restrict__ es, float* __restrict__ denom)
{
    int e = blockIdx.x * 256 + threadIdx.x;
    if (e >= N_EDGES) return;
    int s  = ei[e];
    int tg = ei[N_EDGES + e];
    float4 a = *reinterpret_cast<const float4*>(ssrc + (size_t)s  * NH);
    float4 b = *reinterpret_cast<const float4*>(strg + (size_t)tg * NH);
    float z0 = a.x + b.x, z1 = a.y + b.y, z2 = a.z + b.z, z3 = a.w + b.w;
    z0 = (z0 >= 0.f) ? z0 : 0.2f * z0;
    z1 = (z1 >= 0.f) ? z1 : 0.2f * z1;
    z2 = (z2 >= 0.f) ? z2 : 0.2f * z2;
    z3 = (z3 >= 0.f) ? z3 : 0.2f * z3;
    float4 r = make_float4(expf(z0), expf(z1), expf(z2), expf(z3));
    *reinterpret_cast<float4*>(es + (size_t)e * NH) = r;
    atomicAdd(denom + (size_t)tg * NH + 0, r.x);
    atomicAdd(denom + (size_t)tg * NH + 1, r.y);
    atomicAdd(denom + (size_t)tg * NH + 2, r.z);
    atomicAdd(denom + (size_t)tg * NH + 3, r.w);
}

// ---------------------------------------------------------------------------
// K3: aggregation. Thread per (edge, f): for each head h,
//     out[trg, h*16+f] += proj[src, h*16+f] * es[e,h]/(denom[trg,h]+1e-16)
// ---------------------------------------------------------------------------
__global__ __launch_bounds__(256) void k3_agg(
    const int* __restrict__ ei,
    const float* __restrict__ proj, const float* __restrict__ es,
    const float* __restrict__ denom, float* __restrict__ outv)
{
    int gid = blockIdx.x * 256 + threadIdx.x;     // < E*16 = 12.8M
    if (gid >= N_EDGES * 16) return;
    int e = gid >> 4;
    int f = gid & 15;
    int s  = ei[e];
    int tg = ei[N_EDGES + e];
    float4 ev = *reinterpret_cast<const float4*>(es    + (size_t)e  * NH);
    float4 dv = *reinterpret_cast<const float4*>(denom + (size_t)tg * NH);
    float at[4];
    at[0] = ev.x / (dv.x + 1e-16f);
    at[1] = ev.y / (dv.y + 1e-16f);
    at[2] = ev.z / (dv.z + 1e-16f);
    at[3] = ev.w / (dv.w + 1e-16f);
    const float* __restrict__ ps = proj + (size_t)s  * COUT + f;
    float*       __restrict__ po = outv + (size_t)tg * COUT + f;
    #pragma unroll
    for (int h = 0; h < NH; ++h) {
        float p = ps[h * FOUT];
        atomicAdd(po + h * FOUT, at[h] * p);
    }
}

// ---------------------------------------------------------------------------
// K4: in-place ELU on d_out (float4 over 3.2M floats)
// ---------------------------------------------------------------------------
__global__ __launch_bounds__(256) void k4_elu(float* __restrict__ outv)
{
    int i = blockIdx.x * 256 + threadIdx.x;       // float4 index, < 800000
    if (i >= (N_NODES * COUT) / 4) return;
    float4 v = reinterpret_cast<float4*>(outv)[i];
    v.x = (v.x > 0.f) ? v.x : expm1f(v.x);
    v.y = (v.y > 0.f) ? v.y : expm1f(v.y);
    v.z = (v.z > 0.f) ? v.z : expm1f(v.z);
    v.w = (v.w > 0.f) ? v.w : expm1f(v.w);
    reinterpret_cast<float4*>(outv)[i] = v;
}

extern "C" void kernel_launch(void* const* d_in, const int* in_sizes, int n_in,
                              void* d_out, int out_size, void* d_ws, size_t ws_size,
                              hipStream_t stream)
{
    const float* x     = (const float*)d_in[0];
    const int*   ei    = (const int*)  d_in[1];   // [2, E] int32
    const float* wproj = (const float*)d_in[2];
    const float* asrc  = (const float*)d_in[3];
    const float* atrg  = (const float*)d_in[4];
    const float* wskip = (const float*)d_in[5];
    float* outv = (float*)d_out;

    // workspace layout (floats)
    float* ws    = (float*)d_ws;
    float* proj  = ws;                                   // N*64  = 3.2M
    float* ssrc  = proj + (size_t)N_NODES * COUT;        // N*4
    float* strg  = ssrc + (size_t)N_NODES * NH;          // N*4
    float* denom = strg + (size_t)N_NODES * NH;          // N*4
    float* es    = denom + (size_t)N_NODES * NH;         // E*4  = 3.2M

    hipMemsetAsync(denom, 0, (size_t)N_NODES * NH * sizeof(float), stream);

    // K1: 32 nodes per block
    int k1_blocks = (N_NODES + 31) / 32;
    k1_proj<<<k1_blocks, 256, 0, stream>>>(x, wproj, wskip, asrc, atrg,
                                           proj, ssrc, strg, outv);

    // K2: one thread per edge
    int k2_blocks = (N_EDGES + 255) / 256;
    k2_score<<<k2_blocks, 256, 0, stream>>>(ei, ssrc, strg, es, denom);

    // K3: 16 threads per edge
    int k3_blocks = (N_EDGES * 16) / 256;
    k3_agg<<<k3_blocks, 256, 0, stream>>>(ei, proj, es, denom, outv);

    // K4: ELU epilogue
    int k4_blocks = ((N_NODES * COUT) / 4 + 255) / 256;
    k4_elu<<<k4_blocks, 256, 0, stream>>>(outv);
}

// Round 2
// 229.486 us; speedup vs baseline: 1.9698x; 1.9698x over previous
//
#include <hip/hip_runtime.h>
#include <cstddef>

#define N_NODES 50000
#define N_EDGES 800000
#define FIN     128
#define NH      4
#define FOUT    16
#define COUT    64   // NH*FOUT
#define SCAN_BLOCKS ((N_NODES + 255) / 256)   // 196

// ---------------------------------------------------------------------------
// K1: fused projection GEMM (unchanged from round 0).
//   proj[n, 0:64]  = x[n,:] @ w_proj.T      -> ws
//   skip[n, 0:64]  = x[n,:] @ w_skip.T      -> d_out (agg base)
//   s_src[n,h], s_trg[n,h]                  -> ws
// ---------------------------------------------------------------------------
__global__ __launch_bounds__(256) void k1_proj(
    const float* __restrict__ x,
    const float* __restrict__ wproj, const float* __restrict__ wskip,
    const float* __restrict__ asrc,  const float* __restrict__ atrg,
    float* __restrict__ proj, float* __restrict__ ssrc, float* __restrict__ strg,
    float* __restrict__ outv)
{
    __shared__ float xs[32][FIN];
    const int t  = threadIdx.x;
    const int n0 = blockIdx.x * 32;

    #pragma unroll
    for (int i = 0; i < 4; ++i) {
        int idx = t + i * 256;
        int r   = idx >> 5;
        int c   = (idx & 31) * 4;
        int rr  = n0 + r; if (rr >= N_NODES) rr = N_NODES - 1;
        *reinterpret_cast<float4*>(&xs[r][c]) =
            *reinterpret_cast<const float4*>(x + (size_t)rr * FIN + c);
    }
    __syncthreads();

    const int ty = t >> 5;
    const int tx = t & 31;
    const int r0 = ty * 4;
    const bool isSkip = (tx >= 16);
    const int cc = (tx & 15) * 4;
    const float* __restrict__ W = isSkip ? wskip : wproj;

    float acc[4][4];
    #pragma unroll
    for (int a = 0; a < 4; ++a)
        #pragma unroll
        for (int b = 0; b < 4; ++b) acc[a][b] = 0.f;

    for (int k = 0; k < FIN; k += 4) {
        float4 wv[4];
        #pragma unroll
        for (int b = 0; b < 4; ++b)
            wv[b] = *reinterpret_cast<const float4*>(W + (size_t)(cc + b) * FIN + k);
        #pragma unroll
        for (int a = 0; a < 4; ++a) {
            float4 xv = *reinterpret_cast<const float4*>(&xs[r0 + a][k]);
            #pragma unroll
            for (int b = 0; b < 4; ++b)
                acc[a][b] += xv.x * wv[b].x + xv.y * wv[b].y
                           + xv.z * wv[b].z + xv.w * wv[b].w;
        }
    }

    if (!isSkip) {
        const int h  = tx >> 2;
        const int f0 = cc & 15;
        const float as0 = asrc[h * FOUT + f0 + 0], as1 = asrc[h * FOUT + f0 + 1],
                    as2 = asrc[h * FOUT + f0 + 2], as3 = asrc[h * FOUT + f0 + 3];
        const float at0 = atrg[h * FOUT + f0 + 0], at1 = atrg[h * FOUT + f0 + 1],
                    at2 = atrg[h * FOUT + f0 + 2], at3 = atrg[h * FOUT + f0 + 3];
        #pragma unroll
        for (int a = 0; a < 4; ++a) {
            int n = n0 + r0 + a;
            float4 v = make_float4(acc[a][0], acc[a][1], acc[a][2], acc[a][3]);
            float ps = v.x * as0 + v.y * as1 + v.z * as2 + v.w * as3;
            float pt = v.x * at0 + v.y * at1 + v.z * at2 + v.w * at3;
            ps += __shfl_xor(ps, 1); ps += __shfl_xor(ps, 2);
            pt += __shfl_xor(pt, 1); pt += __shfl_xor(pt, 2);
            if (n < N_NODES) {
                *reinterpret_cast<float4*>(proj + (size_t)n * COUT + cc) = v;
                if ((tx & 3) == 0) {
                    ssrc[(size_t)n * NH + h] = ps;
                    strg[(size_t)n * NH + h] = pt;
                }
            }
        }
    } else {
        #pragma unroll
        for (int a = 0; a < 4; ++a) {
            int n = n0 + r0 + a;
            if (n < N_NODES) {
                float4 v = make_float4(acc[a][0], acc[a][1], acc[a][2], acc[a][3]);
                *reinterpret_cast<float4*>(outv + (size_t)n * COUT + cc) = v;
            }
        }
    }
}

// ---------------------------------------------------------------------------
// CSR build, pass 1: rank within target bucket + degree histogram.
// Only atomics in the whole pipeline: 800k int fetch-adds.
// ---------------------------------------------------------------------------
__global__ __launch_bounds__(256) void k_rank(
    const int* __restrict__ ei, int* __restrict__ deg, int* __restrict__ rank)
{
    int e = blockIdx.x * 256 + threadIdx.x;
    if (e >= N_EDGES) return;
    int tg = ei[N_EDGES + e];
    rank[e] = atomicAdd(deg + tg, 1);
}

// ---------------------------------------------------------------------------
// Exclusive scan of deg[50000] -> rowptr. 3-kernel hierarchical scan.
// ---------------------------------------------------------------------------
__global__ __launch_bounds__(256) void scan_a(
    const int* __restrict__ deg, int* __restrict__ tmpExc, int* __restrict__ bsum)
{
    __shared__ int sm[256];
    int t = threadIdx.x;
    int i = blockIdx.x * 256 + t;
    int v = (i < N_NODES) ? deg[i] : 0;
    sm[t] = v; __syncthreads();
    #pragma unroll
    for (int off = 1; off < 256; off <<= 1) {
        int x = (t >= off) ? sm[t - off] : 0;
        __syncthreads();
        sm[t] += x;
        __syncthreads();
    }
    if (i < N_NODES) tmpExc[i] = sm[t] - v;
    if (t == 255) bsum[blockIdx.x] = sm[t];
}

__global__ __launch_bounds__(256) void scan_b(
    const int* __restrict__ bsum, int* __restrict__ bOff)
{
    __shared__ int sm[256];
    int t = threadIdx.x;
    int v = (t < SCAN_BLOCKS) ? bsum[t] : 0;
    sm[t] = v; __syncthreads();
    #pragma unroll
    for (int off = 1; off < 256; off <<= 1) {
        int x = (t >= off) ? sm[t - off] : 0;
        __syncthreads();
        sm[t] += x;
        __syncthreads();
    }
    if (t < SCAN_BLOCKS) bOff[t] = sm[t] - v;
}

__global__ __launch_bounds__(256) void scan_c(
    const int* __restrict__ tmpExc, const int* __restrict__ bOff,
    int* __restrict__ rowptr)
{
    int i = blockIdx.x * 256 + threadIdx.x;
    if (i < N_NODES) rowptr[i] = tmpExc[i] + bOff[i >> 8];
}

// ---------------------------------------------------------------------------
// CSR build, pass 2: atomic-free scatter of src node ids.
// ---------------------------------------------------------------------------
__global__ __launch_bounds__(256) void k_scatter(
    const int* __restrict__ ei, const int* __restrict__ rowptr,
    const int* __restrict__ rank, int* __restrict__ srcs)
{
    int e = blockIdx.x * 256 + threadIdx.x;
    if (e >= N_EDGES) return;
    int s  = ei[e];
    int tg = ei[N_EDGES + e];
    srcs[rowptr[tg] + rank[e]] = s;
}

// ---------------------------------------------------------------------------
// K3: fused gather-softmax-aggregate-skip-ELU. One wave per target node,
// lane = output feature. attn division hoisted after the loop:
//   out[n,f] = (sum_e es * proj[src,f]) / (sum_e es) + skip[n,f]  -> ELU.
// No atomics, single coalesced output write.
// ---------------------------------------------------------------------------
__global__ __launch_bounds__(256) void k3_gather(
    const int* __restrict__ rowptr, const int* __restrict__ deg,
    const int* __restrict__ srcs,
    const float* __restrict__ ssrc, const float* __restrict__ strg,
    const float* __restrict__ proj, float* __restrict__ outv)
{
    const int lane = threadIdx.x & 63;
    const int node = __builtin_amdgcn_readfirstlane(blockIdx.x * 4 + (threadIdx.x >> 6));
    if (node >= N_NODES) return;
    const int h = lane >> 4;                    // head of this lane's feature
    const int begin = rowptr[node];
    const int dg    = deg[node];
    const float st  = strg[(size_t)node * NH + h];

    float acc = 0.f, dsum = 0.f;
    for (int i = 0; i < dg; ++i) {
        int s = srcs[begin + i];                // wave-uniform (scalar) load
        float z = ssrc[(size_t)s * NH + h] + st;
        z = (z >= 0.f) ? z : 0.2f * z;
        float ez = __expf(z);
        dsum += ez;
        acc += ez * proj[(size_t)s * COUT + lane];   // coalesced 256B gather
    }
    float o = acc / (dsum + 1e-16f) + outv[(size_t)node * COUT + lane];
    o = (o > 0.f) ? o : expm1f(o);
    outv[(size_t)node * COUT + lane] = o;
}

extern "C" void kernel_launch(void* const* d_in, const int* in_sizes, int n_in,
                              void* d_out, int out_size, void* d_ws, size_t ws_size,
                              hipStream_t stream)
{
    const float* x     = (const float*)d_in[0];
    const int*   ei    = (const int*)  d_in[1];   // [2, E] int32
    const float* wproj = (const float*)d_in[2];
    const float* asrc  = (const float*)d_in[3];
    const float* atrg  = (const float*)d_in[4];
    const float* wskip = (const float*)d_in[5];
    float* outv = (float*)d_out;

    // workspace layout
    float* proj  = (float*)d_ws;                         // N*64  floats
    float* ssrc  = proj + (size_t)N_NODES * COUT;        // N*4
    float* strg  = ssrc + (size_t)N_NODES * NH;          // N*4
    int* deg     = (int*)(strg + (size_t)N_NODES * NH);  // N
    int* tmpExc  = deg    + N_NODES;                     // N
    int* bsum    = tmpExc + N_NODES;                     // 256
    int* bOff    = bsum   + 256;                         // 256
    int* rowptr  = bOff   + 256;                         // N
    int* rank    = rowptr + N_NODES;                     // E
    int* srcs    = rank   + N_EDGES;                     // E

    hipMemsetAsync(deg, 0, (size_t)N_NODES * sizeof(int), stream);

    int k1_blocks = (N_NODES + 31) / 32;
    k1_proj<<<k1_blocks, 256, 0, stream>>>(x, wproj, wskip, asrc, atrg,
                                           proj, ssrc, strg, outv);

    int e_blocks = (N_EDGES + 255) / 256;
    k_rank<<<e_blocks, 256, 0, stream>>>(ei, deg, rank);

    scan_a<<<SCAN_BLOCKS, 256, 0, stream>>>(deg, tmpExc, bsum);
    scan_b<<<1, 256, 0, stream>>>(bsum, bOff);
    scan_c<<<SCAN_BLOCKS, 256, 0, stream>>>(tmpExc, bOff, rowptr);

    k_scatter<<<e_blocks, 256, 0, stream>>>(ei, rowptr, rank, srcs);

    int k3_blocks = (N_NODES + 3) / 4;
    k3_gather<<<k3_blocks, 256, 0, stream>>>(rowptr, deg, srcs,
                                             ssrc, strg, proj, outv);
}

// Round 3
// 152.356 us; speedup vs baseline: 2.9670x; 1.5063x over previous
//
#include <hip/hip_runtime.h>
#include <cstddef>

#define N_NODES 50000
#define N_EDGES 800000
#define FIN     128
#define NH      4
#define FOUT    16
#define COUT    64   // NH*FOUT
#define STRIPS  (N_NODES / 16)                // 3125 (exact, no tail)
#define SCAN_BLOCKS ((N_NODES + 255) / 256)   // 196

typedef __bf16 bf16x8 __attribute__((ext_vector_type(8)));
typedef float  f32x4  __attribute__((ext_vector_type(4)));

// ---------------------------------------------------------------------------
// K0: pack [w_proj; w_skip] -> wb[128][128] bf16 (rows 0-63 proj, 64-127 skip)
// ---------------------------------------------------------------------------
__global__ __launch_bounds__(256) void k0_wcvt(
    const float* __restrict__ wproj, const float* __restrict__ wskip,
    __bf16* __restrict__ wb)
{
    int i = blockIdx.x * 256 + threadIdx.x;   // float4 index, 4096 total
    if (i >= (128 * FIN) / 4) return;
    int row = i >> 5;                         // 32 float4 per row
    float4 v = (row < 64) ? reinterpret_cast<const float4*>(wproj)[i]
                          : reinterpret_cast<const float4*>(wskip)[i - 2048];
    __bf16* o = wb + (size_t)i * 4;
    o[0] = (__bf16)v.x; o[1] = (__bf16)v.y;
    o[2] = (__bf16)v.z; o[3] = (__bf16)v.w;
}

// ---------------------------------------------------------------------------
// K1: MFMA projection. One wave per (strip of 16 rows) x (half: proj|skip).
//   half=0: proj[strip rows][0:64] + fused s_src/s_trg epilogue
//   half=1: skip -> d_out (aggregation base)
// No LDS, no barriers. B (W) in registers, A converted f32->bf16 in-flight.
// MFMA 16x16x32 layouts (m89/m91): A row=lane&15, k=(lane>>4)*8+e;
// B col=lane&15; D col=lane&15, row=(lane>>4)*4+reg.
// ---------------------------------------------------------------------------
__global__ __launch_bounds__(256) void k1_mfma(
    const float* __restrict__ x, const __bf16* __restrict__ wb,
    const float* __restrict__ asrc, const float* __restrict__ atrg,
    float* __restrict__ proj, float* __restrict__ ssrc, float* __restrict__ strg,
    float* __restrict__ outv)
{
    const int lane  = threadIdx.x & 63;
    const int wid   = blockIdx.x * 4 + (threadIdx.x >> 6);
    const int strip = wid >> 1;
    const int half  = wid & 1;
    if (strip >= STRIPS) return;
    const int r = lane & 15;          // A-row / B-col / D-col within tile
    const int g = lane >> 4;          // k-slice group (8 elems each)
    const int row0 = strip * 16;

    // B fragments: 4 col-tiles (= heads for half==0) x 4 K-steps
    bf16x8 bfr[4][4];
    #pragma unroll
    for (int j = 0; j < 4; ++j) {
        const __bf16* wrow = wb + (size_t)(half * 64 + j * 16 + r) * FIN;
        #pragma unroll
        for (int kk = 0; kk < 4; ++kk)
            bfr[j][kk] = *reinterpret_cast<const bf16x8*>(wrow + kk * 32 + g * 8);
    }

    // A fragments: x[row0+r][kk*32 + g*8 .. +8], f32 -> bf16
    const float* xrow = x + (size_t)(row0 + r) * FIN + g * 8;
    bf16x8 afr[4];
    #pragma unroll
    for (int kk = 0; kk < 4; ++kk) {
        float4 u0 = *reinterpret_cast<const float4*>(xrow + kk * 32);
        float4 u1 = *reinterpret_cast<const float4*>(xrow + kk * 32 + 4);
        bf16x8 a;
        a[0] = (__bf16)u0.x; a[1] = (__bf16)u0.y;
        a[2] = (__bf16)u0.z; a[3] = (__bf16)u0.w;
        a[4] = (__bf16)u1.x; a[5] = (__bf16)u1.y;
        a[6] = (__bf16)u1.z; a[7] = (__bf16)u1.w;
        afr[kk] = a;
    }

    f32x4 acc[4] = {{0.f,0.f,0.f,0.f},{0.f,0.f,0.f,0.f},
                    {0.f,0.f,0.f,0.f},{0.f,0.f,0.f,0.f}};
    #pragma unroll
    for (int kk = 0; kk < 4; ++kk)
        #pragma unroll
        for (int j = 0; j < 4; ++j)
            acc[j] = __builtin_amdgcn_mfma_f32_16x16x32_bf16(
                         afr[kk], bfr[j][kk], acc[j], 0, 0, 0);

    // store 16x64 tile
    float* outp = half ? outv : proj;
    #pragma unroll
    for (int j = 0; j < 4; ++j)
        #pragma unroll
        for (int q = 0; q < 4; ++q)
            outp[(size_t)(row0 + g * 4 + q) * COUT + j * 16 + r] = acc[j][q];

    // fused attention logits (proj half only): head == col-tile j
    if (!half) {
        #pragma unroll
        for (int j = 0; j < 4; ++j) {
            const float as = asrc[j * 16 + r];
            const float at = atrg[j * 16 + r];
            #pragma unroll
            for (int q = 0; q < 4; ++q) {
                float ts = acc[j][q] * as;
                float tt = acc[j][q] * at;
                ts += __shfl_xor(ts, 1); ts += __shfl_xor(ts, 2);
                ts += __shfl_xor(ts, 4); ts += __shfl_xor(ts, 8);
                tt += __shfl_xor(tt, 1); tt += __shfl_xor(tt, 2);
                tt += __shfl_xor(tt, 4); tt += __shfl_xor(tt, 8);
                if (r == 0) {
                    int n = row0 + g * 4 + q;
                    ssrc[(size_t)n * NH + j] = ts;
                    strg[(size_t)n * NH + j] = tt;
                }
            }
        }
    }
}

// ---------------------------------------------------------------------------
// CSR build, pass 1: rank within target bucket + degree histogram.
// ---------------------------------------------------------------------------
__global__ __launch_bounds__(256) void k_rank(
    const int* __restrict__ ei, int* __restrict__ deg, int* __restrict__ rank)
{
    int e = blockIdx.x * 256 + threadIdx.x;
    if (e >= N_EDGES) return;
    int tg = ei[N_EDGES + e];
    rank[e] = atomicAdd(deg + tg, 1);
}

// ---------------------------------------------------------------------------
// Exclusive scan of deg[50000] -> rowptr. 3-kernel hierarchical scan.
// ---------------------------------------------------------------------------
__global__ __launch_bounds__(256) void scan_a(
    const int* __restrict__ deg, int* __restrict__ tmpExc, int* __restrict__ bsum)
{
    __shared__ int sm[256];
    int t = threadIdx.x;
    int i = blockIdx.x * 256 + t;
    int v = (i < N_NODES) ? deg[i] : 0;
    sm[t] = v; __syncthreads();
    #pragma unroll
    for (int off = 1; off < 256; off <<= 1) {
        int x = (t >= off) ? sm[t - off] : 0;
        __syncthreads();
        sm[t] += x;
        __syncthreads();
    }
    if (i < N_NODES) tmpExc[i] = sm[t] - v;
    if (t == 255) bsum[blockIdx.x] = sm[t];
}

__global__ __launch_bounds__(256) void scan_b(
    const int* __restrict__ bsum, int* __restrict__ bOff)
{
    __shared__ int sm[256];
    int t = threadIdx.x;
    int v = (t < SCAN_BLOCKS) ? bsum[t] : 0;
    sm[t] = v; __syncthreads();
    #pragma unroll
    for (int off = 1; off < 256; off <<= 1) {
        int x = (t >= off) ? sm[t - off] : 0;
        __syncthreads();
        sm[t] += x;
        __syncthreads();
    }
    if (t < SCAN_BLOCKS) bOff[t] = sm[t] - v;
}

__global__ __launch_bounds__(256) void scan_c(
    const int* __restrict__ tmpExc, const int* __restrict__ bOff,
    int* __restrict__ rowptr)
{
    int i = blockIdx.x * 256 + threadIdx.x;
    if (i < N_NODES) rowptr[i] = tmpExc[i] + bOff[i >> 8];
}

// ---------------------------------------------------------------------------
// CSR build, pass 2: atomic-free scatter of src node ids.
// ---------------------------------------------------------------------------
__global__ __launch_bounds__(256) void k_scatter(
    const int* __restrict__ ei, const int* __restrict__ rowptr,
    const int* __restrict__ rank, int* __restrict__ srcs)
{
    int e = blockIdx.x * 256 + threadIdx.x;
    if (e >= N_EDGES) return;
    int s  = ei[e];
    int tg = ei[N_EDGES + e];
    srcs[rowptr[tg] + rank[e]] = s;
}

// ---------------------------------------------------------------------------
// K3: fused gather-softmax-aggregate-skip-ELU. One wave per target node,
// lane = output feature; softmax division hoisted after the loop.
// ---------------------------------------------------------------------------
__global__ __launch_bounds__(256) void k3_gather(
    const int* __restrict__ rowptr, const int* __restrict__ deg,
    const int* __restrict__ srcs,
    const float* __restrict__ ssrc, const float* __restrict__ strg,
    const float* __restrict__ proj, float* __restrict__ outv)
{
    const int lane = threadIdx.x & 63;
    const int node = __builtin_amdgcn_readfirstlane(blockIdx.x * 4 + (threadIdx.x >> 6));
    if (node >= N_NODES) return;
    const int h = lane >> 4;
    const int begin = rowptr[node];
    const int dg    = deg[node];
    const float st  = strg[(size_t)node * NH + h];

    float acc = 0.f, dsum = 0.f;
    for (int i = 0; i < dg; ++i) {
        int s = srcs[begin + i];
        float z = ssrc[(size_t)s * NH + h] + st;
        z = (z >= 0.f) ? z : 0.2f * z;
        float ez = __expf(z);
        dsum += ez;
        acc += ez * proj[(size_t)s * COUT + lane];
    }
    float o = acc / (dsum + 1e-16f) + outv[(size_t)node * COUT + lane];
    o = (o > 0.f) ? o : expm1f(o);
    outv[(size_t)node * COUT + lane] = o;
}

extern "C" void kernel_launch(void* const* d_in, const int* in_sizes, int n_in,
                              void* d_out, int out_size, void* d_ws, size_t ws_size,
                              hipStream_t stream)
{
    const float* x     = (const float*)d_in[0];
    const int*   ei    = (const int*)  d_in[1];   // [2, E] int32
    const float* wproj = (const float*)d_in[2];
    const float* asrc  = (const float*)d_in[3];
    const float* atrg  = (const float*)d_in[4];
    const float* wskip = (const float*)d_in[5];
    float* outv = (float*)d_out;

    // workspace layout
    float* proj  = (float*)d_ws;                         // N*64 floats
    float* ssrc  = proj + (size_t)N_NODES * COUT;        // N*4
    float* strg  = ssrc + (size_t)N_NODES * NH;          // N*4
    int* deg     = (int*)(strg + (size_t)N_NODES * NH);  // N
    int* tmpExc  = deg    + N_NODES;                     // N
    int* bsum    = tmpExc + N_NODES;                     // 256
    int* bOff    = bsum   + 256;                         // 256
    int* rowptr  = bOff   + 256;                         // N
    int* rank    = rowptr + N_NODES;                     // E
    int* srcs    = rank   + N_EDGES;                     // E
    __bf16* wb   = (__bf16*)(srcs + N_EDGES);            // 128*128 bf16

    hipMemsetAsync(deg, 0, (size_t)N_NODES * sizeof(int), stream);

    k0_wcvt<<<16, 256, 0, stream>>>(wproj, wskip, wb);

    int k1_blocks = (STRIPS * 2 + 3) / 4;   // 1563
    k1_mfma<<<k1_blocks, 256, 0, stream>>>(x, wb, asrc, atrg,
                                           proj, ssrc, strg, outv);

    int e_blocks = (N_EDGES + 255) / 256;
    k_rank<<<e_blocks, 256, 0, stream>>>(ei, deg, rank);

    scan_a<<<SCAN_BLOCKS, 256, 0, stream>>>(deg, tmpExc, bsum);
    scan_b<<<1, 256, 0, stream>>>(bsum, bOff);
    scan_c<<<SCAN_BLOCKS, 256, 0, stream>>>(tmpExc, bOff, rowptr);

    k_scatter<<<e_blocks, 256, 0, stream>>>(ei, rowptr, rank, srcs);

    int k3_blocks = (N_NODES + 3) / 4;
    k3_gather<<<k3_blocks, 256, 0, stream>>>(rowptr, deg, srcs,
                                             ssrc, strg, proj, outv);
}

// Round 4
// 123.413 us; speedup vs baseline: 3.6628x; 1.2345x over previous
//
#include <hip/hip_runtime.h>
#include <cstddef>

#define N_NODES 50000
#define N_EDGES 800000
#define FIN     128
#define NH      4
#define FOUT    16
#define COUT    64   // NH*FOUT
#define STRIPS  (N_NODES / 16)                // 3125 (exact, no tail)
#define SCAN_BLOCKS ((N_NODES + 255) / 256)   // 196

typedef __bf16 bf16x8 __attribute__((ext_vector_type(8)));
typedef float  f32x4  __attribute__((ext_vector_type(4)));

// ---------------------------------------------------------------------------
// K0: pack [w_proj; w_skip] -> wb[128][128] bf16 (rows 0-63 proj, 64-127 skip)
// ---------------------------------------------------------------------------
__global__ __launch_bounds__(256) void k0_wcvt(
    const float* __restrict__ wproj, const float* __restrict__ wskip,
    __bf16* __restrict__ wb)
{
    int i = blockIdx.x * 256 + threadIdx.x;   // float4 index, 4096 total
    if (i >= (128 * FIN) / 4) return;
    int row = i >> 5;                         // 32 float4 per row
    float4 v = (row < 64) ? reinterpret_cast<const float4*>(wproj)[i]
                          : reinterpret_cast<const float4*>(wskip)[i - 2048];
    __bf16* o = wb + (size_t)i * 4;
    o[0] = (__bf16)v.x; o[1] = (__bf16)v.y;
    o[2] = (__bf16)v.z; o[3] = (__bf16)v.w;
}

// ---------------------------------------------------------------------------
// K1: MFMA projection. One wave per (strip of 16 rows) x (half: proj|skip).
//   half=0: proj (bf16, k3's gather table) + fused s_src/s_trg epilogue
//   half=1: skip (f32) -> d_out (aggregation base)
// MFMA 16x16x32 layouts (m89/m91): A row=lane&15, k=(lane>>4)*8+e;
// B col=lane&15; D col=lane&15, row=(lane>>4)*4+reg.
// ---------------------------------------------------------------------------
__global__ __launch_bounds__(256) void k1_mfma(
    const float* __restrict__ x, const __bf16* __restrict__ wb,
    const float* __restrict__ asrc, const float* __restrict__ atrg,
    __bf16* __restrict__ projb, float* __restrict__ ssrc, float* __restrict__ strg,
    float* __restrict__ outv)
{
    const int lane  = threadIdx.x & 63;
    const int wid   = blockIdx.x * 4 + (threadIdx.x >> 6);
    const int strip = wid >> 1;
    const int half  = wid & 1;
    if (strip >= STRIPS) return;
    const int r = lane & 15;          // A-row / B-col / D-col within tile
    const int g = lane >> 4;          // k-slice group (8 elems each)
    const int row0 = strip * 16;

    // B fragments: 4 col-tiles (= heads for half==0) x 4 K-steps
    bf16x8 bfr[4][4];
    #pragma unroll
    for (int j = 0; j < 4; ++j) {
        const __bf16* wrow = wb + (size_t)(half * 64 + j * 16 + r) * FIN;
        #pragma unroll
        for (int kk = 0; kk < 4; ++kk)
            bfr[j][kk] = *reinterpret_cast<const bf16x8*>(wrow + kk * 32 + g * 8);
    }

    // A fragments: x[row0+r][kk*32 + g*8 .. +8], f32 -> bf16
    const float* xrow = x + (size_t)(row0 + r) * FIN + g * 8;
    bf16x8 afr[4];
    #pragma unroll
    for (int kk = 0; kk < 4; ++kk) {
        float4 u0 = *reinterpret_cast<const float4*>(xrow + kk * 32);
        float4 u1 = *reinterpret_cast<const float4*>(xrow + kk * 32 + 4);
        bf16x8 a;
        a[0] = (__bf16)u0.x; a[1] = (__bf16)u0.y;
        a[2] = (__bf16)u0.z; a[3] = (__bf16)u0.w;
        a[4] = (__bf16)u1.x; a[5] = (__bf16)u1.y;
        a[6] = (__bf16)u1.z; a[7] = (__bf16)u1.w;
        afr[kk] = a;
    }

    f32x4 acc[4] = {{0.f,0.f,0.f,0.f},{0.f,0.f,0.f,0.f},
                    {0.f,0.f,0.f,0.f},{0.f,0.f,0.f,0.f}};
    #pragma unroll
    for (int kk = 0; kk < 4; ++kk)
        #pragma unroll
        for (int j = 0; j < 4; ++j)
            acc[j] = __builtin_amdgcn_mfma_f32_16x16x32_bf16(
                         afr[kk], bfr[j][kk], acc[j], 0, 0, 0);

    if (!half) {
        // bf16 proj store (16x64 tile)
        #pragma unroll
        for (int j = 0; j < 4; ++j)
            #pragma unroll
            for (int q = 0; q < 4; ++q)
                projb[(size_t)(row0 + g * 4 + q) * COUT + j * 16 + r] =
                    (__bf16)acc[j][q];
        // fused attention logits: head == col-tile j
        #pragma unroll
        for (int j = 0; j < 4; ++j) {
            const float as = asrc[j * 16 + r];
            const float at = atrg[j * 16 + r];
            #pragma unroll
            for (int q = 0; q < 4; ++q) {
                float ts = acc[j][q] * as;
                float tt = acc[j][q] * at;
                ts += __shfl_xor(ts, 1); ts += __shfl_xor(ts, 2);
                ts += __shfl_xor(ts, 4); ts += __shfl_xor(ts, 8);
                tt += __shfl_xor(tt, 1); tt += __shfl_xor(tt, 2);
                tt += __shfl_xor(tt, 4); tt += __shfl_xor(tt, 8);
                if (r == 0) {
                    int n = row0 + g * 4 + q;
                    ssrc[(size_t)n * NH + j] = ts;
                    strg[(size_t)n * NH + j] = tt;
                }
            }
        }
    } else {
        // f32 skip store -> d_out
        #pragma unroll
        for (int j = 0; j < 4; ++j)
            #pragma unroll
            for (int q = 0; q < 4; ++q)
                outv[(size_t)(row0 + g * 4 + q) * COUT + j * 16 + r] = acc[j][q];
    }
}

// ---------------------------------------------------------------------------
// CSR build, pass 1: rank within target bucket + degree histogram.
// ---------------------------------------------------------------------------
__global__ __launch_bounds__(256) void k_rank(
    const int* __restrict__ ei, int* __restrict__ deg, int* __restrict__ rank)
{
    int e = blockIdx.x * 256 + threadIdx.x;
    if (e >= N_EDGES) return;
    int tg = ei[N_EDGES + e];
    rank[e] = atomicAdd(deg + tg, 1);
}

// ---------------------------------------------------------------------------
// Exclusive scan of deg[50000] -> rowptr. 3-kernel hierarchical scan.
// ---------------------------------------------------------------------------
__global__ __launch_bounds__(256) void scan_a(
    const int* __restrict__ deg, int* __restrict__ tmpExc, int* __restrict__ bsum)
{
    __shared__ int sm[256];
    int t = threadIdx.x;
    int i = blockIdx.x * 256 + t;
    int v = (i < N_NODES) ? deg[i] : 0;
    sm[t] = v; __syncthreads();
    #pragma unroll
    for (int off = 1; off < 256; off <<= 1) {
        int x = (t >= off) ? sm[t - off] : 0;
        __syncthreads();
        sm[t] += x;
        __syncthreads();
    }
    if (i < N_NODES) tmpExc[i] = sm[t] - v;
    if (t == 255) bsum[blockIdx.x] = sm[t];
}

__global__ __launch_bounds__(256) void scan_b(
    const int* __restrict__ bsum, int* __restrict__ bOff)
{
    __shared__ int sm[256];
    int t = threadIdx.x;
    int v = (t < SCAN_BLOCKS) ? bsum[t] : 0;
    sm[t] = v; __syncthreads();
    #pragma unroll
    for (int off = 1; off < 256; off <<= 1) {
        int x = (t >= off) ? sm[t - off] : 0;
        __syncthreads();
        sm[t] += x;
        __syncthreads();
    }
    if (t < SCAN_BLOCKS) bOff[t] = sm[t] - v;
}

__global__ __launch_bounds__(256) void scan_c(
    const int* __restrict__ tmpExc, const int* __restrict__ bOff,
    int* __restrict__ rowptr)
{
    int i = blockIdx.x * 256 + threadIdx.x;
    if (i < N_NODES) rowptr[i] = tmpExc[i] + bOff[i >> 8];
}

// ---------------------------------------------------------------------------
// CSR build, pass 2: atomic-free scatter of src node ids.
// ---------------------------------------------------------------------------
__global__ __launch_bounds__(256) void k_scatter(
    const int* __restrict__ ei, const int* __restrict__ rowptr,
    const int* __restrict__ rank, int* __restrict__ srcs)
{
    int e = blockIdx.x * 256 + threadIdx.x;
    if (e >= N_EDGES) return;
    int s  = ei[e];
    int tg = ei[N_EDGES + e];
    srcs[rowptr[tg] + rank[e]] = s;
}

// ---------------------------------------------------------------------------
// K3: fused gather-softmax-aggregate-skip-ELU. One wave per target node,
// lane = output feature; softmax division hoisted after the loop.
// Edge loop unrolled x4: 4 independent src->proj gather chains in flight.
// proj is bf16 (128B/edge instead of 256B).
// ---------------------------------------------------------------------------
__global__ __launch_bounds__(256) void k3_gather(
    const int* __restrict__ rowptr, const int* __restrict__ deg,
    const int* __restrict__ srcs,
    const float* __restrict__ ssrc, const float* __restrict__ strg,
    const __bf16* __restrict__ projb, float* __restrict__ outv)
{
    const int lane = threadIdx.x & 63;
    const int node = __builtin_amdgcn_readfirstlane(blockIdx.x * 4 + (threadIdx.x >> 6));
    if (node >= N_NODES) return;
    const int h = lane >> 4;
    const int begin = rowptr[node];
    const int dg    = deg[node];
    const float st  = strg[(size_t)node * NH + h];
    const float skip = outv[(size_t)node * COUT + lane];  // hoisted, overlaps loop

    float acc = 0.f, dsum = 0.f;
    int i = 0;
    for (; i + 4 <= dg; i += 4) {
        // issue all loads first: 4 independent gather chains
        int s0 = srcs[begin + i + 0];
        int s1 = srcs[begin + i + 1];
        int s2 = srcs[begin + i + 2];
        int s3 = srcs[begin + i + 3];
        float a0 = ssrc[(size_t)s0 * NH + h];
        float a1 = ssrc[(size_t)s1 * NH + h];
        float a2 = ssrc[(size_t)s2 * NH + h];
        float a3 = ssrc[(size_t)s3 * NH + h];
        float p0 = (float)projb[(size_t)s0 * COUT + lane];
        float p1 = (float)projb[(size_t)s1 * COUT + lane];
        float p2 = (float)projb[(size_t)s2 * COUT + lane];
        float p3 = (float)projb[(size_t)s3 * COUT + lane];
        float z0 = a0 + st, z1 = a1 + st, z2 = a2 + st, z3 = a3 + st;
        z0 = (z0 >= 0.f) ? z0 : 0.2f * z0;
        z1 = (z1 >= 0.f) ? z1 : 0.2f * z1;
        z2 = (z2 >= 0.f) ? z2 : 0.2f * z2;
        z3 = (z3 >= 0.f) ? z3 : 0.2f * z3;
        float e0 = __expf(z0), e1 = __expf(z1), e2 = __expf(z2), e3 = __expf(z3);
        dsum += (e0 + e1) + (e2 + e3);
        acc += e0 * p0; acc += e1 * p1; acc += e2 * p2; acc += e3 * p3;
    }
    for (; i < dg; ++i) {
        int s = srcs[begin + i];
        float z = ssrc[(size_t)s * NH + h] + st;
        z = (z >= 0.f) ? z : 0.2f * z;
        float ez = __expf(z);
        float p  = (float)projb[(size_t)s * COUT + lane];
        dsum += ez;
        acc += ez * p;
    }
    float o = acc / (dsum + 1e-16f) + skip;
    o = (o > 0.f) ? o : expm1f(o);
    outv[(size_t)node * COUT + lane] = o;
}

extern "C" void kernel_launch(void* const* d_in, const int* in_sizes, int n_in,
                              void* d_out, int out_size, void* d_ws, size_t ws_size,
                              hipStream_t stream)
{
    const float* x     = (const float*)d_in[0];
    const int*   ei    = (const int*)  d_in[1];   // [2, E] int32
    const float* wproj = (const float*)d_in[2];
    const float* asrc  = (const float*)d_in[3];
    const float* atrg  = (const float*)d_in[4];
    const float* wskip = (const float*)d_in[5];
    float* outv = (float*)d_out;

    // workspace layout (proj region kept at N*64 floats; bf16 uses half of it)
    __bf16* projb = (__bf16*)d_ws;                        // N*64 bf16
    float* base  = (float*)d_ws;
    float* ssrc  = base + (size_t)N_NODES * COUT;         // N*4
    float* strg  = ssrc + (size_t)N_NODES * NH;           // N*4
    int* deg     = (int*)(strg + (size_t)N_NODES * NH);   // N
    int* tmpExc  = deg    + N_NODES;                      // N
    int* bsum    = tmpExc + N_NODES;                      // 256
    int* bOff    = bsum   + 256;                          // 256
    int* rowptr  = bOff   + 256;                          // N
    int* rank    = rowptr + N_NODES;                      // E
    int* srcs    = rank   + N_EDGES;                      // E
    __bf16* wb   = (__bf16*)(srcs + N_EDGES);             // 128*128 bf16

    hipMemsetAsync(deg, 0, (size_t)N_NODES * sizeof(int), stream);

    k0_wcvt<<<16, 256, 0, stream>>>(wproj, wskip, wb);

    int k1_blocks = (STRIPS * 2 + 3) / 4;   // 1563
    k1_mfma<<<k1_blocks, 256, 0, stream>>>(x, wb, asrc, atrg,
                                           projb, ssrc, strg, outv);

    int e_blocks = (N_EDGES + 255) / 256;
    k_rank<<<e_blocks, 256, 0, stream>>>(ei, deg, rank);

    scan_a<<<SCAN_BLOCKS, 256, 0, stream>>>(deg, tmpExc, bsum);
    scan_b<<<1, 256, 0, stream>>>(bsum, bOff);
    scan_c<<<SCAN_BLOCKS, 256, 0, stream>>>(tmpExc, bOff, rowptr);

    k_scatter<<<e_blocks, 256, 0, stream>>>(ei, rowptr, rank, srcs);

    int k3_blocks = (N_NODES + 3) / 4;
    k3_gather<<<k3_blocks, 256, 0, stream>>>(rowptr, deg, srcs,
                                             ssrc, strg, projb, outv);
}